// Round 1
// baseline (49583.279 us; speedup 1.0000x reference)
//
#include <hip/hip_runtime.h>
#include <hip/hip_bf16.h>
#include <math.h>

#define SEQ 2048
#define DM 1024
#define DH 64
#define NH 16
#define DFF 4096
#define NL 12
#define NVOCAB 50257

// ---------------------------------------------------------------------------
// Embedding + sinusoidal PE:  x[s,d] = emb[tokens[s], d] + PE(s, d)
// PE[s,2j] = sin(s / 10000^(2j/1024)), PE[s,2j+1] = cos(same)
// ---------------------------------------------------------------------------
__global__ __launch_bounds__(256) void embed_kernel(
    const int* __restrict__ tokens, const float* __restrict__ emb,
    float* __restrict__ x)
{
    const int s = blockIdx.x;
    const int tid = threadIdx.x;
    const int tok = tokens[s];
    #pragma unroll
    for (int i = 0; i < 4; ++i) {
        const int d = tid + i * 256;
        const int j = d >> 1;
        const double ang = (double)s * exp((double)(-2 * j) * (log(10000.0) / 1024.0));
        const float pe = (d & 1) ? (float)cos(ang) : (float)sin(ang);
        x[(size_t)s * DM + d] = emb[(size_t)tok * DM + d] + pe;
    }
}

// ---------------------------------------------------------------------------
// Generic fp32 tiled GEMM: C[M,N] = A[M,K] @ B[K,N] (+bias, optional relu)
// 64x64 tile per 256-thread block, 4x4 per thread, BK=16.
// B/C can be batched via strideB/strideC (blockIdx.z), A shared across batch.
// M % 64 == 0 and K % 16 == 0 assumed; N bounds handled.
// ---------------------------------------------------------------------------
__global__ __launch_bounds__(256) void gemm64(
    const float* __restrict__ A, const float* __restrict__ B,
    float* __restrict__ C, const float* __restrict__ bias,
    int M, int N, int K, long long strideB, long long strideC, int relu)
{
    __shared__ float As[16][65];
    __shared__ float Bs[16][64];

    const float* Bp = B + (size_t)blockIdx.z * strideB;
    float* Cp = C + (size_t)blockIdx.z * strideC;

    const int m0 = blockIdx.y * 64;
    const int n0 = blockIdx.x * 64;
    const int tid = threadIdx.x;
    const int tx = tid & 15, ty = tid >> 4;

    const int a_m = tid >> 2;          // 0..63
    const int a_k = (tid & 3) * 4;     // 0,4,8,12
    const int b_k = tid >> 4;          // 0..15
    const int b_n = (tid & 15) * 4;    // 0..60

    float acc[4][4] = {};
    const bool nvec = ((N & 3) == 0);

    for (int k0 = 0; k0 < K; k0 += 16) {
        // A tile 64x16 -> As[k][m] (transposed)
        const float4 av = *(const float4*)(A + (size_t)(m0 + a_m) * K + k0 + a_k);
        As[a_k + 0][a_m] = av.x;
        As[a_k + 1][a_m] = av.y;
        As[a_k + 2][a_m] = av.z;
        As[a_k + 3][a_m] = av.w;
        // B tile 16x64 -> Bs[k][n]
        const int bn = n0 + b_n;
        const float* Brow = Bp + (size_t)(k0 + b_k) * N;
        float4 bv;
        if (nvec && bn + 3 < N) {
            bv = *(const float4*)(Brow + bn);
        } else {
            bv.x = (bn + 0 < N) ? Brow[bn + 0] : 0.f;
            bv.y = (bn + 1 < N) ? Brow[bn + 1] : 0.f;
            bv.z = (bn + 2 < N) ? Brow[bn + 2] : 0.f;
            bv.w = (bn + 3 < N) ? Brow[bn + 3] : 0.f;
        }
        *(float4*)&Bs[b_k][b_n] = bv;
        __syncthreads();
        #pragma unroll
        for (int k = 0; k < 16; ++k) {
            float am[4], bb[4];
            #pragma unroll
            for (int i = 0; i < 4; ++i) am[i] = As[k][ty * 4 + i];
            #pragma unroll
            for (int j = 0; j < 4; ++j) bb[j] = Bs[k][tx * 4 + j];
            #pragma unroll
            for (int i = 0; i < 4; ++i)
                #pragma unroll
                for (int j = 0; j < 4; ++j)
                    acc[i][j] += am[i] * bb[j];
        }
        __syncthreads();
    }

    #pragma unroll
    for (int i = 0; i < 4; ++i) {
        const int m = m0 + ty * 4 + i;
        #pragma unroll
        for (int j = 0; j < 4; ++j) {
            const int n = n0 + tx * 4 + j;
            if (n < N) {
                float vv = acc[i][j];
                if (bias) vv += bias[n];
                if (relu) vv = fmaxf(vv, 0.f);
                Cp[(size_t)m * N + n] = vv;
            }
        }
    }
}

// ---------------------------------------------------------------------------
// Causal attention, one block per (query row s, head h).
// Q,K,V layout: [H][S][64].  Output written concat-head: MO[s][h*64+k].
// ---------------------------------------------------------------------------
__global__ __launch_bounds__(256) void attn_kernel(
    const float* __restrict__ Q, const float* __restrict__ K,
    const float* __restrict__ V, float* __restrict__ MO)
{
    const int s = blockIdx.x;
    const int h = blockIdx.y;
    const int tid = threadIdx.x;

    __shared__ float qs[64];
    __shared__ float sc[SEQ];
    __shared__ float rbuf[4];
    __shared__ float pvbuf[4][64];

    const float* Qh = Q + ((size_t)h * SEQ + s) * DH;
    const float* Kh = K + (size_t)h * SEQ * DH;
    const float* Vh = V + (size_t)h * SEQ * DH;

    if (tid < 64) qs[tid] = Qh[tid];
    __syncthreads();

    // scores[t] = (q . k_t) / 8 for t <= s
    for (int t = tid; t <= s; t += 256) {
        const float4* kr = (const float4*)(Kh + (size_t)t * DH);
        float acc = 0.f;
        #pragma unroll
        for (int k4 = 0; k4 < 16; ++k4) {
            const float4 kv = kr[k4];
            acc += qs[k4 * 4 + 0] * kv.x + qs[k4 * 4 + 1] * kv.y +
                   qs[k4 * 4 + 2] * kv.z + qs[k4 * 4 + 3] * kv.w;
        }
        sc[t] = acc * 0.125f;
    }
    __syncthreads();

    // max reduce
    float m = -1e30f;
    for (int t = tid; t <= s; t += 256) m = fmaxf(m, sc[t]);
    #pragma unroll
    for (int off = 32; off; off >>= 1) m = fmaxf(m, __shfl_xor(m, off, 64));
    if ((tid & 63) == 0) rbuf[tid >> 6] = m;
    __syncthreads();
    const float mall = fmaxf(fmaxf(rbuf[0], rbuf[1]), fmaxf(rbuf[2], rbuf[3]));

    // exp + sum reduce
    float ssum = 0.f;
    for (int t = tid; t <= s; t += 256) {
        const float p = __expf(sc[t] - mall);
        sc[t] = p;
        ssum += p;
    }
    #pragma unroll
    for (int off = 32; off; off >>= 1) ssum += __shfl_xor(ssum, off, 64);
    __syncthreads();  // protect rbuf reuse; also makes sc[] writes visible
    if ((tid & 63) == 0) rbuf[tid >> 6] = ssum;
    __syncthreads();
    const float inv = 1.f / (rbuf[0] + rbuf[1] + rbuf[2] + rbuf[3]);

    // PV: thread (g, kk), g strides t, kk is head dim
    const int g = tid >> 6, kk = tid & 63;
    float acc = 0.f;
    for (int t = g; t <= s; t += 4) acc += sc[t] * Vh[(size_t)t * DH + kk];
    pvbuf[g][kk] = acc;
    __syncthreads();
    if (tid < 64) {
        const float o = (pvbuf[0][tid] + pvbuf[1][tid] + pvbuf[2][tid] + pvbuf[3][tid]) * inv;
        MO[(size_t)s * DM + h * DH + tid] = o;
    }
}

// ---------------------------------------------------------------------------
// x = LayerNorm(x + t) * g + b   (one block per row; bias already in t)
// ---------------------------------------------------------------------------
__global__ __launch_bounds__(256) void ln_res_kernel(
    float* __restrict__ x, const float* __restrict__ t,
    const float* __restrict__ gg, const float* __restrict__ bb)
{
    const int row = blockIdx.x;
    const int tid = threadIdx.x;
    float* xr = x + (size_t)row * DM;
    const float* tr = t + (size_t)row * DM;

    float v[4];
    float s1 = 0.f, s2 = 0.f;
    #pragma unroll
    for (int i = 0; i < 4; ++i) {
        const int d = tid + i * 256;
        v[i] = xr[d] + tr[d];
        s1 += v[i];
        s2 += v[i] * v[i];
    }
    #pragma unroll
    for (int off = 32; off; off >>= 1) {
        s1 += __shfl_xor(s1, off, 64);
        s2 += __shfl_xor(s2, off, 64);
    }
    __shared__ float r1[4], r2[4];
    const int lane = tid & 63, wv = tid >> 6;
    if (lane == 0) { r1[wv] = s1; r2[wv] = s2; }
    __syncthreads();
    const float tot1 = r1[0] + r1[1] + r1[2] + r1[3];
    const float tot2 = r2[0] + r2[1] + r2[2] + r2[3];
    const float mu = tot1 * (1.f / 1024.f);
    const float var = tot2 * (1.f / 1024.f) - mu * mu;
    const float rs = rsqrtf(var + 1e-5f);
    #pragma unroll
    for (int i = 0; i < 4; ++i) {
        const int d = tid + i * 256;
        xr[d] = (v[i] - mu) * rs * gg[d] + bb[d];
    }
}

// ---------------------------------------------------------------------------
extern "C" void kernel_launch(void* const* d_in, const int* in_sizes, int n_in,
                              void* d_out, int out_size, void* d_ws, size_t ws_size,
                              hipStream_t stream)
{
    const int*   tokens = (const int*)d_in[0];
    const float* emb  = (const float*)d_in[1];
    const float* Wq   = (const float*)d_in[2];
    const float* Wk   = (const float*)d_in[3];
    const float* Wv   = (const float*)d_in[4];
    const float* Wo   = (const float*)d_in[5];
    const float* bo   = (const float*)d_in[6];
    const float* ln1g = (const float*)d_in[7];
    const float* ln1b = (const float*)d_in[8];
    const float* W1   = (const float*)d_in[9];
    const float* b1   = (const float*)d_in[10];
    const float* W2   = (const float*)d_in[11];
    const float* b2   = (const float*)d_in[12];
    const float* ln2g = (const float*)d_in[13];
    const float* ln2b = (const float*)d_in[14];
    const float* Wout = (const float*)d_in[15];
    const float* bout = (const float*)d_in[16];
    float* out = (float*)d_out;

    float* ws = (float*)d_ws;
    const size_t SQD = (size_t)SEQ * DM;   // 2 M floats
    float* x   = ws;                        // [S, DM]
    float* tmp = ws + SQD;                  // [S, DM] GEMM outputs (Wo, W2)
    float* q   = ws + 2 * SQD;              // [H, S, 64]
    float* k   = ws + 3 * SQD;
    float* v   = ws + 4 * SQD;
    float* mo  = ws + 5 * SQD;              // [S, DM] concat heads
    float* h1  = ws + 2 * SQD;              // [S, DFF] aliases q..mo (dead by then)

    embed_kernel<<<SEQ, 256, 0, stream>>>(tokens, emb, x);

    const long long sB = (long long)DM * DH;       // per-head weight stride
    const long long sC = (long long)SEQ * DH;      // per-head output stride

    for (int l = 0; l < NL; ++l) {
        const float* wq = Wq + (size_t)l * NH * DM * DH;
        const float* wk = Wk + (size_t)l * NH * DM * DH;
        const float* wv = Wv + (size_t)l * NH * DM * DH;
        const float* wo = Wo + (size_t)l * DM * DM;
        const float* w1 = W1 + (size_t)l * DM * DFF;
        const float* w2 = W2 + (size_t)l * DFF * DM;

        dim3 gqkv(1, SEQ / 64, NH);
        gemm64<<<gqkv, 256, 0, stream>>>(x, wq, q, nullptr, SEQ, DH, DM, sB, sC, 0);
        gemm64<<<gqkv, 256, 0, stream>>>(x, wk, k, nullptr, SEQ, DH, DM, sB, sC, 0);
        gemm64<<<gqkv, 256, 0, stream>>>(x, wv, v, nullptr, SEQ, DH, DM, sB, sC, 0);

        attn_kernel<<<dim3(SEQ, NH), 256, 0, stream>>>(q, k, v, mo);

        gemm64<<<dim3(DM / 64, SEQ / 64, 1), 256, 0, stream>>>(
            mo, wo, tmp, bo + (size_t)l * DM, SEQ, DM, DM, 0, 0, 0);
        ln_res_kernel<<<SEQ, 256, 0, stream>>>(x, tmp, ln1g + (size_t)l * DM, ln1b + (size_t)l * DM);

        gemm64<<<dim3(DFF / 64, SEQ / 64, 1), 256, 0, stream>>>(
            x, w1, h1, b1 + (size_t)l * DFF, SEQ, DFF, DM, 0, 0, 1);
        gemm64<<<dim3(DM / 64, SEQ / 64, 1), 256, 0, stream>>>(
            h1, w2, tmp, b2 + (size_t)l * DM, SEQ, DM, DFF, 0, 0, 0);
        ln_res_kernel<<<SEQ, 256, 0, stream>>>(x, tmp, ln2g + (size_t)l * DM, ln2b + (size_t)l * DM);
    }

    gemm64<<<dim3((NVOCAB + 63) / 64, SEQ / 64, 1), 256, 0, stream>>>(
        x, Wout, out, bout, SEQ, NVOCAB, DM, 0, 0, 0);
}